// Round 1
// baseline (697.195 us; speedup 1.0000x reference)
//
#include <hip/hip_runtime.h>
#include <math.h>

#define NUM_TOK 8192
#define DIM     2048
#define NEXP    64
#define CAP     128

#define TM      32            // tokens per block (kernel A)
#define BK      64            // K-chunk
#define NT      256           // threads per block (kernel A)
#define NBLKA   (NUM_TOK/TM)  // 256 blocks
#define NCHUNK  (DIM/BK)      // 32 K-chunks

// LDS strides (floats). Both row strides are multiples of 4 floats (16B) so
// float4 (ds_read_b128) stays aligned; chosen to avoid >2-way bank aliasing
// on the hot main-loop reads (2-way is free per m136).
#define XS_STR  72            // BK+8
#define WS_STR  68            // NEXP+4
#define LG_STR  (NEXP+1)

// zero-fill partition of combine+dispatch: 2*S*E*C floats / 256 blocks
#define ZFLT    524288u       // floats per block
#define ZPER    (ZFLT/NCHUNK) // 16384 floats per K-chunk
// per thread per chunk: 16384/256 = 64 floats = 16 float4 stores

__global__ __launch_bounds__(NT) void gate_fused(
    const float* __restrict__ x, const float* __restrict__ wg,
    float* __restrict__ out,
    int* __restrict__ expert_idx, float* __restrict__ gate_top,
    float* __restrict__ me_partial, int* __restrict__ counts)
{
    __shared__ __align__(16) float xs[TM * XS_STR];      // 9216 B
    __shared__ __align__(16) float wss[BK * WS_STR];     // 17408 B (transposed [kk][e])
    __shared__ __align__(16) float logits_s[TM * LG_STR];
    __shared__ float me_s[NEXP];
    __shared__ int   cnt_s[NEXP];

    const int tid = threadIdx.x;
    const int bid = blockIdx.x;
    const int tx  = tid & 15;   // expert group: experts 4tx..4tx+3
    const int ty  = tid >> 4;   // token group:  tokens 2ty, 2ty+1
    const int tok0 = bid * TM;

    if (tid < NEXP) { me_s[tid] = 0.0f; cnt_s[tid] = 0; }

    float acc[2][4] = {};

    // zero-fill base for this block's slice of combine+dispatch
    float* zbase = out + 1 + (size_t)bid * ZFLT;
    const float4 z4 = make_float4(0.f, 0.f, 0.f, 0.f);

    for (int kc = 0; kc < NCHUNK; ++kc) {
        const int k0 = kc * BK;

        // ---- interleaved zero stores (independent VMEM traffic) ----
        {
            float4* zp = (float4*)(zbase + (size_t)kc * ZPER) + tid;
            #pragma unroll
            for (int q = 0; q < 16; ++q) zp[q * NT] = z4;
        }

        // ---- stage x tile [32][64] ----
        #pragma unroll
        for (int q = 0; q < 2; ++q) {
            int id = tid + NT * q;
            int r = id >> 4, cf = id & 15;
            float4 v = *(const float4*)(x + (size_t)(tok0 + r) * DIM + k0 + 4 * cf);
            *(float4*)(&xs[r * XS_STR + 4 * cf]) = v;
        }
        // ---- stage wg tile transposed -> wss[kk][e] ----
        {
            int cf = tid & 15, er = tid >> 4;
            #pragma unroll
            for (int i = 0; i < 4; ++i) {
                int e = er + 16 * i;
                float4 v = *(const float4*)(wg + (size_t)e * DIM + k0 + 4 * cf);
                wss[(4 * cf + 0) * WS_STR + e] = v.x;
                wss[(4 * cf + 1) * WS_STR + e] = v.y;
                wss[(4 * cf + 2) * WS_STR + e] = v.z;
                wss[(4 * cf + 3) * WS_STR + e] = v.w;
            }
        }
        __syncthreads();

        // ---- FMA inner loop: 2 tokens x 4 experts per thread ----
        #pragma unroll
        for (int kk = 0; kk < BK; kk += 4) {
            float4 xa = *(const float4*)(&xs[(2 * ty + 0) * XS_STR + kk]);
            float4 xb = *(const float4*)(&xs[(2 * ty + 1) * XS_STR + kk]);
            #pragma unroll
            for (int j = 0; j < 4; ++j) {
                float4 w = *(const float4*)(&wss[(kk + j) * WS_STR + 4 * tx]);
                float xaj = (&xa.x)[j], xbj = (&xb.x)[j];
                acc[0][0] += xaj * w.x; acc[0][1] += xaj * w.y;
                acc[0][2] += xaj * w.z; acc[0][3] += xaj * w.w;
                acc[1][0] += xbj * w.x; acc[1][1] += xbj * w.y;
                acc[1][2] += xbj * w.z; acc[1][3] += xbj * w.w;
            }
        }
        __syncthreads();
    }

    // ---- logits to LDS ----
    #pragma unroll
    for (int i = 0; i < 2; ++i)
        #pragma unroll
        for (int j = 0; j < 4; ++j)
            logits_s[(2 * ty + i) * LG_STR + 4 * tx + j] = acc[i][j];
    __syncthreads();

    // ---- softmax + argmax: 4 waves x 8 rows, lane = expert ----
    const int lane = tid & 63;
    const int wv   = tid >> 6;
    float me_acc = 0.0f;
    for (int r8 = 0; r8 < 8; ++r8) {
        int row = wv * 8 + r8;
        float v = logits_s[row * LG_STR + lane];
        float m = v; int mi = lane;
        #pragma unroll
        for (int off = 32; off > 0; off >>= 1) {
            float om = __shfl_xor(m, off);
            int  omi = __shfl_xor(mi, off);
            if (om > m || (om == m && omi < mi)) { m = om; mi = omi; }
        }
        float ex = __expf(v - m);
        float s = ex;
        #pragma unroll
        for (int off = 32; off > 0; off >>= 1) s += __shfl_xor(s, off);
        me_acc += ex / s;                 // lane e's softmax prob for this row
        if (lane == mi) {
            int token = tok0 + row;
            expert_idx[token] = mi;
            gate_top[token]   = 1.0f / s; // exp(0)/s: gate of the argmax expert
            atomicAdd(&cnt_s[mi], 1);
        }
    }
    atomicAdd(&me_s[lane], me_acc);
    __syncthreads();
    if (tid < NEXP) {
        me_partial[bid * NEXP + tid] = me_s[tid];
        counts[bid * NEXP + tid]     = cnt_s[tid];
    }
}

// Single block: per-expert exclusive prefix over the 256 block-tiles (token
// order == block order) + l_aux. Deterministic, ~2k scalar iterations.
__global__ __launch_bounds__(64) void prefix_laux(
    const float* __restrict__ me_partial, const int* __restrict__ counts,
    int* __restrict__ block_off, float* __restrict__ out)
{
    int e = threadIdx.x;  // 0..63, one expert per lane
    float me = 0.0f;
    for (int b = 0; b < NBLKA; ++b) me += me_partial[b * NEXP + e];
    int run = 0;
    for (int b = 0; b < NBLKA; ++b) {
        block_off[b * NEXP + e] = run;
        run += counts[b * NEXP + e];
    }
    float ce = (float)run / (float)NUM_TOK;
    me = me / (float)NUM_TOK;
    float v = me * ce;
    #pragma unroll
    for (int off = 32; off > 0; off >>= 1) v += __shfl_xor(v, off);
    if (e == 0) out[0] = v * (float)NEXP;  // mean(me*ce)*E*E == sum(me*ce)*E
}

// Scatter the <=8192 nonzeros: rank within 32-token tile + global offset.
__global__ __launch_bounds__(64) void scatter_k(
    const int* __restrict__ expert_idx, const float* __restrict__ gate_top,
    const int* __restrict__ block_off, float* __restrict__ out)
{
    __shared__ int es[TM];
    int t = threadIdx.x, b = blockIdx.x;
    if (t < TM) es[t] = expert_idx[b * TM + t];
    __syncthreads();
    if (t < TM) {
        int e = es[t];
        int rank = 0;
        for (int u = 0; u < t; ++u) rank += (es[u] == e) ? 1 : 0;
        int loc = block_off[b * NEXP + e] + rank;
        if (loc < CAP) {
            size_t sidx = (size_t)(b * TM + t);
            size_t off  = sidx * (NEXP * CAP) + (size_t)e * CAP + loc;
            out[1 + off] = gate_top[b * TM + t];                       // combine
            out[1 + (size_t)NUM_TOK * NEXP * CAP + off] = 1.0f;        // dispatch
        }
    }
}

extern "C" void kernel_launch(void* const* d_in, const int* in_sizes, int n_in,
                              void* d_out, int out_size, void* d_ws, size_t ws_size,
                              hipStream_t stream)
{
    const float* x  = (const float*)d_in[0];
    const float* wg = (const float*)d_in[1];
    float* out = (float*)d_out;

    char* ws = (char*)d_ws;
    int*   expert_idx = (int*)  (ws);            //  8192 * 4 = 32 KB
    float* gate_top   = (float*)(ws + 32768);    //  8192 * 4 = 32 KB
    float* me_partial = (float*)(ws + 65536);    //  256*64*4 = 64 KB
    int*   counts     = (int*)  (ws + 131072);   //  64 KB
    int*   block_off  = (int*)  (ws + 196608);   //  64 KB  (total 256 KB)

    // Kernel A zero-fills all of combine+dispatch itself (no memset needed);
    // out[0] (l_aux) is unconditionally written by prefix_laux.
    gate_fused<<<NBLKA, NT, 0, stream>>>(x, wg, out, expert_idx, gate_top,
                                         me_partial, counts);
    prefix_laux<<<1, 64, 0, stream>>>(me_partial, counts, block_off, out);
    scatter_k<<<NBLKA, 64, 0, stream>>>(expert_idx, gate_top, block_off, out);
}